// Round 3
// baseline (281.837 us; speedup 1.0000x reference)
//
#include <hip/hip_runtime.h>
#include <math.h>

#define DIM 394
#define KP  416      // padded K = 13*32
#define NT  13       // K-steps
#define NP  448      // padded N = 28*16
#define BN_EPS 1e-5f

typedef __bf16 bf16x8 __attribute__((ext_vector_type(8)));
typedef float  f32x4  __attribute__((ext_vector_type(4)));

__device__ inline void gload_lds16(const void* g, void* l) {
    __builtin_amdgcn_global_load_lds(
        (const __attribute__((address_space(1))) void*)g,
        (__attribute__((address_space(3))) void*)l, 16, 0, 0);
}

// wave-uniform layout probe: int64 edge_index has all odd 32-bit words == 0
__device__ inline bool edges_are_int32(const int* ei) {
    int l = threadIdx.x & 63;
    unsigned long long b = __ballot(ei[2 * l + 1] != 0);
    return b != 0ULL;
}

// ---------------------------------------------------------------------------
// ws layout: deg[n] (becomes dinv) | y[2n] | xs[2n] | (align) Bp | Pk | Ok
// ---------------------------------------------------------------------------

// block-role-split prep: init deg/y, pack Pk/Ok, pack B fragments
__global__ void prep_kernel(const float* __restrict__ Wg, const float* __restrict__ bg,
                            const float* __restrict__ gamma, const float* __restrict__ beta,
                            const float* __restrict__ mean, const float* __restrict__ var,
                            const float* __restrict__ fcw,
                            float* deg, float* y, float4* Pk, float* Ok,
                            bf16x8* Bp, int n, int nb0) {
    int b = blockIdx.x, t = threadIdx.x;
    if (b < nb0) {                       // init
        int v = b * 256 + t;
        if (v < n) {
            deg[v] = 1.0f;               // self-loop
            y[2 * v] = 0.0f;
            y[2 * v + 1] = 0.0f;
        }
    } else if (b < nb0 + 2) {            // Pk/Ok: per-k GCN+BN constants
        int k = (b - nb0) * 256 + t;
        if (k < KP) {
            float4 p = make_float4(0.f, 0.f, 0.f, 0.f);
            float o = 0.f;
            if (k < DIM) {
                p.x = Wg[2 * k];
                p.y = Wg[2 * k + 1];
                p.z = bg[k];
                float s = gamma[k] * rsqrtf(var[k] + BN_EPS);
                p.w = s;
                o = beta[k] - s * mean[k];
            }
            Pk[k] = p;
            Ok[k] = o;
        }
    } else {                             // B = fc_w^T packed bf16 fragments
        int idx = (b - nb0 - 2) * 256 + t;
        if (idx < NT * 4 * NP) {
            int col = idx % NP;
            int r   = idx / NP;          // ks*4 + kc
            int k0  = r * 8;
            bf16x8 v;
            #pragma unroll
            for (int q = 0; q < 8; ++q) {
                int k = k0 + q;
                float f = (col < DIM && k < DIM) ? fcw[col * DIM + k] : 0.0f;
                v[q] = (__bf16)f;
            }
            Bp[idx] = v;
        }
    }
}

// degree count: 4 edges/thread, vectorized dst loads
__global__ void deg_kernel(const int* __restrict__ ei, float* deg, int e) {
    bool is32 = edges_are_int32(ei);
    int i0 = (blockIdx.x * blockDim.x + threadIdx.x) * 4;
    if (i0 >= e) return;
    if ((e & 3) == 0) {
        int d0, d1, d2, d3;
        if (is32) {
            int4 v = *reinterpret_cast<const int4*>(&ei[e + i0]);
            d0 = v.x; d1 = v.y; d2 = v.z; d3 = v.w;
        } else {
            int4 a = *reinterpret_cast<const int4*>(&ei[2 * (e + i0)]);
            int4 b = *reinterpret_cast<const int4*>(&ei[2 * (e + i0) + 4]);
            d0 = a.x; d1 = a.z; d2 = b.x; d3 = b.z;
        }
        atomicAdd(&deg[d0], 1.0f);
        atomicAdd(&deg[d1], 1.0f);
        atomicAdd(&deg[d2], 1.0f);
        atomicAdd(&deg[d3], 1.0f);
    } else {
        for (int j = 0; j < 4 && i0 + j < e; ++j) {
            int d = is32 ? ei[e + i0 + j] : ei[2 * (e + i0 + j)];
            atomicAdd(&deg[d], 1.0f);
        }
    }
}

// xs[i] = dinv[i]*x[i]; deg[i] <- dinv[i] (in place)
__global__ void xs_kernel(const float2* __restrict__ x2, float* deg,
                          float2* __restrict__ xs2, int n) {
    int i = blockIdx.x * blockDim.x + threadIdx.x;
    if (i < n) {
        float di = rsqrtf(deg[i]);
        deg[i] = di;
        float2 xv = x2[i];
        xs2[i] = make_float2(di * xv.x, di * xv.y);
    }
}

// scatter: y[d] += xs[s]   (4 edges/thread)
__global__ void scatter_kernel(const int* __restrict__ ei,
                               const float2* __restrict__ xs2,
                               float* __restrict__ y, int e) {
    bool is32 = edges_are_int32(ei);
    int i0 = (blockIdx.x * blockDim.x + threadIdx.x) * 4;
    if (i0 >= e) return;
    if ((e & 3) == 0) {
        int s0, s1, s2, s3, d0, d1, d2, d3;
        if (is32) {
            int4 sv = *reinterpret_cast<const int4*>(&ei[i0]);
            int4 dv = *reinterpret_cast<const int4*>(&ei[e + i0]);
            s0 = sv.x; s1 = sv.y; s2 = sv.z; s3 = sv.w;
            d0 = dv.x; d1 = dv.y; d2 = dv.z; d3 = dv.w;
        } else {
            int4 a = *reinterpret_cast<const int4*>(&ei[2 * i0]);
            int4 b = *reinterpret_cast<const int4*>(&ei[2 * i0 + 4]);
            int4 c = *reinterpret_cast<const int4*>(&ei[2 * (e + i0)]);
            int4 d = *reinterpret_cast<const int4*>(&ei[2 * (e + i0) + 4]);
            s0 = a.x; s1 = a.z; s2 = b.x; s3 = b.z;
            d0 = c.x; d1 = c.z; d2 = d.x; d3 = d.z;
        }
        float2 m0 = xs2[s0], m1 = xs2[s1], m2 = xs2[s2], m3 = xs2[s3];
        atomicAdd(&y[2 * d0],     m0.x); atomicAdd(&y[2 * d0 + 1], m0.y);
        atomicAdd(&y[2 * d1],     m1.x); atomicAdd(&y[2 * d1 + 1], m1.y);
        atomicAdd(&y[2 * d2],     m2.x); atomicAdd(&y[2 * d2 + 1], m2.y);
        atomicAdd(&y[2 * d3],     m3.x); atomicAdd(&y[2 * d3 + 1], m3.y);
    } else {
        for (int j = 0; j < 4 && i0 + j < e; ++j) {
            int s = is32 ? ei[i0 + j]     : ei[2 * (i0 + j)];
            int d = is32 ? ei[e + i0 + j] : ei[2 * (e + i0 + j)];
            float2 m = xs2[s];
            atomicAdd(&y[2 * d],     m.x);
            atomicAdd(&y[2 * d + 1], m.y);
        }
    }
}

// ---------------------------------------------------------------------------
// Fused: h = BN(relu(GCN)) on-the-fly -> bf16 MFMA GEMM -> +fc_b
//        -> z store + log_softmax store. 256 thr / 4 waves, BM=64, BN=448.
// ---------------------------------------------------------------------------
__global__ __launch_bounds__(256, 2)
void gemm_fused(const float* __restrict__ dinv, const float* __restrict__ y,
                const float2* __restrict__ xs2,
                const float4* __restrict__ Pk, const float* __restrict__ Ok,
                const bf16x8* __restrict__ Bp, const float* __restrict__ fcb,
                float* __restrict__ outp, float* __restrict__ z, int n) {
    __shared__ bf16x8 As[2][256];    // [kc(4)][row(64)] per buffer
    __shared__ bf16x8 Bs[2][1792];   // [kc(4)][col(448)] per buffer

    int tid = threadIdx.x;
    int wv  = tid >> 6;
    int l   = tid & 63;
    int cg  = l & 15;
    int kg  = l >> 4;
    int row0 = blockIdx.x * 64;

    int gi = row0 + l;
    float y0 = 0.f, y1 = 0.f;
    if (gi < n) {
        float di = dinv[gi];
        float2 yv = *reinterpret_cast<const float2*>(&y[2 * gi]);
        float2 xv = xs2[gi];
        y0 = di * (yv.x + xv.x);
        y1 = di * (yv.y + xv.y);
    }

    f32x4 acc[4][7];
    #pragma unroll
    for (int a = 0; a < 4; ++a)
        #pragma unroll
        for (int b = 0; b < 7; ++b)
            acc[a][b] = (f32x4){0.f, 0.f, 0.f, 0.f};

    auto stageA = [&](int ks, int buf) {
        int kb = ks * 32 + wv * 8;
        bf16x8 hv;
        #pragma unroll
        for (int q = 0; q < 8; ++q) {
            float4 p = Pk[kb + q];
            float t = fmaf(y0, p.x, fmaf(y1, p.y, p.z));
            t = fmaxf(t, 0.f);
            hv[q] = (__bf16)fmaf(p.w, t, Ok[kb + q]);
        }
        As[buf][wv * 64 + l] = hv;
    };
    auto stageB = [&](int ks, int buf) {
        const char* g = (const char*)Bp + (size_t)ks * 28672 + (size_t)l * 16;
        char* lb = (char*)&Bs[buf][0];
        #pragma unroll
        for (int c = 0; c < 7; ++c) {
            int off = (wv * 7 + c) * 1024;
            gload_lds16(g + off, lb + off);
        }
    };
    auto compute = [&](int buf) {
        bf16x8 af[4];
        #pragma unroll
        for (int rt = 0; rt < 4; ++rt)
            af[rt] = As[buf][kg * 64 + rt * 16 + cg];
        #pragma unroll
        for (int ct = 0; ct < 7; ++ct) {
            bf16x8 bfr = Bs[buf][kg * 448 + wv * 112 + ct * 16 + cg];
            #pragma unroll
            for (int rt = 0; rt < 4; ++rt)
                acc[rt][ct] = __builtin_amdgcn_mfma_f32_16x16x32_bf16(
                                  af[rt], bfr, acc[rt][ct], 0, 0, 0);
        }
    };

    stageB(0, 0);
    stageA(0, 0);
    __syncthreads();
    int buf = 0;
    for (int ks = 0; ks < NT; ++ks) {
        if (ks < NT - 1) { stageB(ks + 1, buf ^ 1); stageA(ks + 1, buf ^ 1); }
        compute(buf);
        __syncthreads();
        buf ^= 1;
    }

    // ---------------- epilogue: bias + log_softmax + stores ----------------
    float* redm = (float*)&As[0][0];
    float* reds = redm + 256;

    int colb = wv * 112;
    float bias[7];
    bool  cv[7];
    #pragma unroll
    for (int ct = 0; ct < 7; ++ct) {
        int c = colb + ct * 16 + cg;
        cv[ct] = (c < DIM);
        bias[ct] = cv[ct] ? fcb[c] : 0.f;
    }
    #pragma unroll
    for (int rt = 0; rt < 4; ++rt)
        #pragma unroll
        for (int ct = 0; ct < 7; ++ct)
            acc[rt][ct] = acc[rt][ct] + bias[ct];

    f32x4 mx[4];
    #pragma unroll
    for (int rt = 0; rt < 4; ++rt) {
        f32x4 m = (f32x4){-1e30f, -1e30f, -1e30f, -1e30f};
        #pragma unroll
        for (int ct = 0; ct < 7; ++ct) {
            if (!cv[ct]) continue;
            #pragma unroll
            for (int j = 0; j < 4; ++j) m[j] = fmaxf(m[j], acc[rt][ct][j]);
        }
        #pragma unroll
        for (int msk = 1; msk < 16; msk <<= 1)
            #pragma unroll
            for (int j = 0; j < 4; ++j)
                m[j] = fmaxf(m[j], __shfl_xor(m[j], msk));
        mx[rt] = m;
    }
    if (cg == 0) {
        #pragma unroll
        for (int rt = 0; rt < 4; ++rt)
            #pragma unroll
            for (int j = 0; j < 4; ++j)
                redm[(rt * 16 + kg * 4 + j) * 4 + wv] = mx[rt][j];
    }
    __syncthreads();
    f32x4 gm[4];
    #pragma unroll
    for (int rt = 0; rt < 4; ++rt)
        #pragma unroll
        for (int j = 0; j < 4; ++j) {
            int r = (rt * 16 + kg * 4 + j) * 4;
            gm[rt][j] = fmaxf(fmaxf(redm[r], redm[r + 1]),
                              fmaxf(redm[r + 2], redm[r + 3]));
        }

    f32x4 sm[4];
    #pragma unroll
    for (int rt = 0; rt < 4; ++rt) {
        f32x4 s = (f32x4){0.f, 0.f, 0.f, 0.f};
        #pragma unroll
        for (int ct = 0; ct < 7; ++ct) {
            if (!cv[ct]) continue;
            #pragma unroll
            for (int j = 0; j < 4; ++j)
                s[j] += __expf(acc[rt][ct][j] - gm[rt][j]);
        }
        #pragma unroll
        for (int msk = 1; msk < 16; msk <<= 1)
            #pragma unroll
            for (int j = 0; j < 4; ++j)
                s[j] += __shfl_xor(s[j], msk);
        sm[rt] = s;
    }
    if (cg == 0) {
        #pragma unroll
        for (int rt = 0; rt < 4; ++rt)
            #pragma unroll
            for (int j = 0; j < 4; ++j)
                reds[(rt * 16 + kg * 4 + j) * 4 + wv] = sm[rt][j];
    }
    __syncthreads();
    f32x4 lse[4];
    #pragma unroll
    for (int rt = 0; rt < 4; ++rt)
        #pragma unroll
        for (int j = 0; j < 4; ++j) {
            int r = (rt * 16 + kg * 4 + j) * 4;
            float t = reds[r] + reds[r + 1] + reds[r + 2] + reds[r + 3];
            lse[rt][j] = gm[rt][j] + __logf(t);
        }

    #pragma unroll
    for (int rt = 0; rt < 4; ++rt)
        #pragma unroll
        for (int j = 0; j < 4; ++j) {
            int grow = row0 + rt * 16 + kg * 4 + j;
            if (grow >= n) continue;
            size_t base = (size_t)grow * DIM;
            float L = lse[rt][j];
            #pragma unroll
            for (int ct = 0; ct < 7; ++ct) {
                if (!cv[ct]) continue;
                int c = colb + ct * 16 + cg;
                float zv = acc[rt][ct][j];
                __builtin_nontemporal_store(zv,     &z[base + c]);
                __builtin_nontemporal_store(zv - L, &outp[base + c]);
            }
        }
}

// ---------------------------------------------------------------------------
extern "C" void kernel_launch(void* const* d_in, const int* in_sizes, int n_in,
                              void* d_out, int out_size, void* d_ws, size_t ws_size,
                              hipStream_t stream) {
    int n = in_sizes[0] / 2;       // 50000 nodes
    int e = in_sizes[1] / 2;       // 800000 edges

    const float* x     = (const float*)d_in[0];
    const int*   ei    = (const int*)d_in[1];
    const float* Wg    = (const float*)d_in[2];
    const float* bg    = (const float*)d_in[3];
    const float* gamma = (const float*)d_in[4];
    const float* beta  = (const float*)d_in[5];
    const float* mean  = (const float*)d_in[6];
    const float* var   = (const float*)d_in[7];
    const float* fcw   = (const float*)d_in[8];
    const float* fcb   = (const float*)d_in[9];

    float* out = (float*)d_out;                 // [n, DIM] log_softmax
    float* z   = out + (size_t)n * DIM;         // [n, DIM] logits

    char* wsb = (char*)d_ws;
    float*  deg = (float*)wsb;                          // n (becomes dinv)
    float*  y   = deg + n;                              // 2n
    float2* xs2 = (float2*)(y + 2 * (size_t)n);         // 2n floats
    size_t off = ((size_t)(5 * n) * 4 + 255) & ~(size_t)255;
    bf16x8* Bp = (bf16x8*)(wsb + off);                  // 13*4*448 * 16B
    off += (size_t)NT * 4 * NP * 16;
    float4* Pk = (float4*)(wsb + off);                  // KP * 16B
    off += (size_t)KP * 16;
    float* Ok  = (float*)(wsb + off);                   // KP * 4B

    int nb0 = (n + 255) / 256;
    int prep_blocks = nb0 + 2 + (NT * 4 * NP + 255) / 256;
    int eb4 = (e / 4 + 255) / 256 + 1;

    prep_kernel<<<prep_blocks, 256, 0, stream>>>(Wg, bg, gamma, beta, mean, var,
                                                 fcw, deg, y, Pk, Ok, Bp, n, nb0);
    deg_kernel<<<eb4, 256, 0, stream>>>(ei, deg, e);
    xs_kernel<<<nb0, 256, 0, stream>>>((const float2*)x, deg, xs2, n);
    scatter_kernel<<<eb4, 256, 0, stream>>>(ei, xs2, y, e);

    int gm = (n + 63) / 64;
    gemm_fused<<<gm, 256, 0, stream>>>(deg, y, xs2, Pk, Ok, Bp, fcb, out, z, n);
}

// Round 4
// 209.552 us; speedup vs baseline: 1.3450x; 1.3450x over previous
//
#include <hip/hip_runtime.h>
#include <math.h>

#define DIM 394
#define KP  416      // padded K = 13*32
#define NT  13       // K-steps
#define NP  448      // padded N = 28*16
#define BN_EPS 1e-5f

typedef __bf16 bf16x8 __attribute__((ext_vector_type(8)));
typedef float  f32x4  __attribute__((ext_vector_type(4)));

// wave-uniform layout probe: int64 edge_index has all odd 32-bit words == 0
__device__ inline bool edges_are_int32(const int* ei) {
    int l = threadIdx.x & 63;
    unsigned long long b = __ballot(ei[2 * l + 1] != 0);
    return b != 0ULL;
}

// ---------------------------------------------------------------------------
// ws layout: deg[n] (becomes dinv) | y[2n] | xs[2n] | (align) Bp | Pk | Ok
// ---------------------------------------------------------------------------

// block-role-split prep: init deg/y, pack Pk/Ok, pack B fragments
__global__ void prep_kernel(const float* __restrict__ Wg, const float* __restrict__ bg,
                            const float* __restrict__ gamma, const float* __restrict__ beta,
                            const float* __restrict__ mean, const float* __restrict__ var,
                            const float* __restrict__ fcw,
                            float* deg, float* y, float4* Pk, float* Ok,
                            bf16x8* Bp, int n, int nb0) {
    int b = blockIdx.x, t = threadIdx.x;
    if (b < nb0) {                       // init
        int v = b * 256 + t;
        if (v < n) {
            deg[v] = 1.0f;               // self-loop
            y[2 * v] = 0.0f;
            y[2 * v + 1] = 0.0f;
        }
    } else if (b < nb0 + 2) {            // Pk/Ok: per-k GCN+BN constants
        int k = (b - nb0) * 256 + t;
        if (k < KP) {
            float4 p = make_float4(0.f, 0.f, 0.f, 0.f);
            float o = 0.f;
            if (k < DIM) {
                p.x = Wg[2 * k];
                p.y = Wg[2 * k + 1];
                p.z = bg[k];
                float s = gamma[k] * rsqrtf(var[k] + BN_EPS);
                p.w = s;
                o = beta[k] - s * mean[k];
            }
            Pk[k] = p;
            Ok[k] = o;
        }
    } else {                             // B = fc_w^T packed bf16 fragments
        int idx = (b - nb0 - 2) * 256 + t;
        if (idx < NT * 4 * NP) {
            int col = idx % NP;
            int r   = idx / NP;          // ks*4 + kc
            int k0  = r * 8;
            bf16x8 v;
            #pragma unroll
            for (int q = 0; q < 8; ++q) {
                int k = k0 + q;
                float f = (col < DIM && k < DIM) ? fcw[col * DIM + k] : 0.0f;
                v[q] = (__bf16)f;
            }
            Bp[idx] = v;
        }
    }
}

// degree count: 4 edges/thread, vectorized dst loads
__global__ void deg_kernel(const int* __restrict__ ei, float* deg, int e) {
    bool is32 = edges_are_int32(ei);
    int i0 = (blockIdx.x * blockDim.x + threadIdx.x) * 4;
    if (i0 >= e) return;
    if ((e & 3) == 0) {
        int d0, d1, d2, d3;
        if (is32) {
            int4 v = *reinterpret_cast<const int4*>(&ei[e + i0]);
            d0 = v.x; d1 = v.y; d2 = v.z; d3 = v.w;
        } else {
            int4 a = *reinterpret_cast<const int4*>(&ei[2 * (e + i0)]);
            int4 b = *reinterpret_cast<const int4*>(&ei[2 * (e + i0) + 4]);
            d0 = a.x; d1 = a.z; d2 = b.x; d3 = b.z;
        }
        atomicAdd(&deg[d0], 1.0f);
        atomicAdd(&deg[d1], 1.0f);
        atomicAdd(&deg[d2], 1.0f);
        atomicAdd(&deg[d3], 1.0f);
    } else {
        for (int j = 0; j < 4 && i0 + j < e; ++j) {
            int d = is32 ? ei[e + i0 + j] : ei[2 * (e + i0 + j)];
            atomicAdd(&deg[d], 1.0f);
        }
    }
}

// xs[i] = dinv[i]*x[i]; deg[i] <- dinv[i] (in place)
__global__ void xs_kernel(const float2* __restrict__ x2, float* deg,
                          float2* __restrict__ xs2, int n) {
    int i = blockIdx.x * blockDim.x + threadIdx.x;
    if (i < n) {
        float di = rsqrtf(deg[i]);
        deg[i] = di;
        float2 xv = x2[i];
        xs2[i] = make_float2(di * xv.x, di * xv.y);
    }
}

// scatter: y[d] += xs[s]   (4 edges/thread)
__global__ void scatter_kernel(const int* __restrict__ ei,
                               const float2* __restrict__ xs2,
                               float* __restrict__ y, int e) {
    bool is32 = edges_are_int32(ei);
    int i0 = (blockIdx.x * blockDim.x + threadIdx.x) * 4;
    if (i0 >= e) return;
    if ((e & 3) == 0) {
        int s0, s1, s2, s3, d0, d1, d2, d3;
        if (is32) {
            int4 sv = *reinterpret_cast<const int4*>(&ei[i0]);
            int4 dv = *reinterpret_cast<const int4*>(&ei[e + i0]);
            s0 = sv.x; s1 = sv.y; s2 = sv.z; s3 = sv.w;
            d0 = dv.x; d1 = dv.y; d2 = dv.z; d3 = dv.w;
        } else {
            int4 a = *reinterpret_cast<const int4*>(&ei[2 * i0]);
            int4 b = *reinterpret_cast<const int4*>(&ei[2 * i0 + 4]);
            int4 c = *reinterpret_cast<const int4*>(&ei[2 * (e + i0)]);
            int4 d = *reinterpret_cast<const int4*>(&ei[2 * (e + i0) + 4]);
            s0 = a.x; s1 = a.z; s2 = b.x; s3 = b.z;
            d0 = c.x; d1 = c.z; d2 = d.x; d3 = d.z;
        }
        float2 m0 = xs2[s0], m1 = xs2[s1], m2 = xs2[s2], m3 = xs2[s3];
        atomicAdd(&y[2 * d0],     m0.x); atomicAdd(&y[2 * d0 + 1], m0.y);
        atomicAdd(&y[2 * d1],     m1.x); atomicAdd(&y[2 * d1 + 1], m1.y);
        atomicAdd(&y[2 * d2],     m2.x); atomicAdd(&y[2 * d2 + 1], m2.y);
        atomicAdd(&y[2 * d3],     m3.x); atomicAdd(&y[2 * d3 + 1], m3.y);
    } else {
        for (int j = 0; j < 4 && i0 + j < e; ++j) {
            int s = is32 ? ei[i0 + j]     : ei[2 * (i0 + j)];
            int d = is32 ? ei[e + i0 + j] : ei[2 * (e + i0 + j)];
            float2 m = xs2[s];
            atomicAdd(&y[2 * d],     m.x);
            atomicAdd(&y[2 * d + 1], m.y);
        }
    }
}

// ---------------------------------------------------------------------------
// Fused: h = BN(relu(GCN)) on-the-fly -> bf16 MFMA GEMM -> +fc_b
//        -> z store + log_softmax store. 256 thr / 4 waves, BM=64, BN=448.
// B fragments read DIRECTLY global->VGPR (Bp is L2-resident, 256B-coalesced),
// register double-buffered. Only As (8KB) lives in LDS -> 1 barrier/K-step,
// no vmcnt(0) drain of B, occupancy limited by VGPR only.
// ---------------------------------------------------------------------------
__global__ __launch_bounds__(256, 2)
void gemm_fused(const float* __restrict__ dinv, const float* __restrict__ y,
                const float2* __restrict__ xs2,
                const float4* __restrict__ Pk, const float* __restrict__ Ok,
                const bf16x8* __restrict__ Bp, const float* __restrict__ fcb,
                float* __restrict__ outp, float* __restrict__ z, int n) {
    __shared__ bf16x8 As[2][256];    // [kc(4)][row(64)] per buffer, 8 KB total

    int tid = threadIdx.x;
    int wv  = tid >> 6;
    int l   = tid & 63;
    int cg  = l & 15;
    int kg  = l >> 4;
    int row0 = blockIdx.x * 64;

    int gi = row0 + l;
    float y0 = 0.f, y1 = 0.f;
    if (gi < n) {
        float di = dinv[gi];
        float2 yv = *reinterpret_cast<const float2*>(&y[2 * gi]);
        float2 xv = xs2[gi];
        y0 = di * (yv.x + xv.x);
        y1 = di * (yv.y + xv.y);
    }

    f32x4 acc[4][7];
    #pragma unroll
    for (int a = 0; a < 4; ++a)
        #pragma unroll
        for (int b = 0; b < 7; ++b)
            acc[a][b] = (f32x4){0.f, 0.f, 0.f, 0.f};

    auto stageA = [&](int ks, int buf) {
        int kb = ks * 32 + wv * 8;
        bf16x8 hv;
        #pragma unroll
        for (int q = 0; q < 8; ++q) {
            float4 p = Pk[kb + q];
            float t = fmaf(y0, p.x, fmaf(y1, p.y, p.z));
            t = fmaxf(t, 0.f);
            hv[q] = (__bf16)fmaf(p.w, t, Ok[kb + q]);
        }
        As[buf][wv * 64 + l] = hv;
    };

    // lane-fixed B base: fragment (ks, ct) is at bptr[ks*4*448 + ct*16]
    const bf16x8* bptr = Bp + (kg * 448 + wv * 112 + cg);

    bf16x8 Bcur[7], Bnxt[7];
    #pragma unroll
    for (int c = 0; c < 7; ++c) Bcur[c] = bptr[c * 16];
    stageA(0, 0);
    __syncthreads();

    int buf = 0;
    for (int ks = 0; ks < NT; ++ks) {
        if (ks < NT - 1) {
            const bf16x8* bn = bptr + (size_t)(ks + 1) * (4 * 448);
            #pragma unroll
            for (int c = 0; c < 7; ++c) Bnxt[c] = bn[c * 16];
            stageA(ks + 1, buf ^ 1);
        }
        bf16x8 af[4];
        #pragma unroll
        for (int rt = 0; rt < 4; ++rt)
            af[rt] = As[buf][kg * 64 + rt * 16 + cg];
        #pragma unroll
        for (int ct = 0; ct < 7; ++ct)
            #pragma unroll
            for (int rt = 0; rt < 4; ++rt)
                acc[rt][ct] = __builtin_amdgcn_mfma_f32_16x16x32_bf16(
                                  af[rt], Bcur[ct], acc[rt][ct], 0, 0, 0);
        __syncthreads();
        #pragma unroll
        for (int c = 0; c < 7; ++c) Bcur[c] = Bnxt[c];
        buf ^= 1;
    }

    // ---------------- epilogue: bias + log_softmax + stores ----------------
    float* redm = (float*)&As[0][0];
    float* reds = redm + 256;

    int colb = wv * 112;
    float bias[7];
    bool  cv[7];
    #pragma unroll
    for (int ct = 0; ct < 7; ++ct) {
        int c = colb + ct * 16 + cg;
        cv[ct] = (c < DIM);
        bias[ct] = cv[ct] ? fcb[c] : 0.f;
    }
    #pragma unroll
    for (int rt = 0; rt < 4; ++rt)
        #pragma unroll
        for (int ct = 0; ct < 7; ++ct)
            acc[rt][ct] = acc[rt][ct] + bias[ct];

    f32x4 mx[4];
    #pragma unroll
    for (int rt = 0; rt < 4; ++rt) {
        f32x4 m = (f32x4){-1e30f, -1e30f, -1e30f, -1e30f};
        #pragma unroll
        for (int ct = 0; ct < 7; ++ct) {
            if (!cv[ct]) continue;
            #pragma unroll
            for (int j = 0; j < 4; ++j) m[j] = fmaxf(m[j], acc[rt][ct][j]);
        }
        #pragma unroll
        for (int msk = 1; msk < 16; msk <<= 1)
            #pragma unroll
            for (int j = 0; j < 4; ++j)
                m[j] = fmaxf(m[j], __shfl_xor(m[j], msk));
        mx[rt] = m;
    }
    if (cg == 0) {
        #pragma unroll
        for (int rt = 0; rt < 4; ++rt)
            #pragma unroll
            for (int j = 0; j < 4; ++j)
                redm[(rt * 16 + kg * 4 + j) * 4 + wv] = mx[rt][j];
    }
    __syncthreads();
    f32x4 gm[4];
    #pragma unroll
    for (int rt = 0; rt < 4; ++rt)
        #pragma unroll
        for (int j = 0; j < 4; ++j) {
            int r = (rt * 16 + kg * 4 + j) * 4;
            gm[rt][j] = fmaxf(fmaxf(redm[r], redm[r + 1]),
                              fmaxf(redm[r + 2], redm[r + 3]));
        }

    f32x4 sm[4];
    #pragma unroll
    for (int rt = 0; rt < 4; ++rt) {
        f32x4 s = (f32x4){0.f, 0.f, 0.f, 0.f};
        #pragma unroll
        for (int ct = 0; ct < 7; ++ct) {
            if (!cv[ct]) continue;
            #pragma unroll
            for (int j = 0; j < 4; ++j)
                s[j] += __expf(acc[rt][ct][j] - gm[rt][j]);
        }
        #pragma unroll
        for (int msk = 1; msk < 16; msk <<= 1)
            #pragma unroll
            for (int j = 0; j < 4; ++j)
                s[j] += __shfl_xor(s[j], msk);
        sm[rt] = s;
    }
    if (cg == 0) {
        #pragma unroll
        for (int rt = 0; rt < 4; ++rt)
            #pragma unroll
            for (int j = 0; j < 4; ++j)
                reds[(rt * 16 + kg * 4 + j) * 4 + wv] = sm[rt][j];
    }
    __syncthreads();
    f32x4 lse[4];
    #pragma unroll
    for (int rt = 0; rt < 4; ++rt)
        #pragma unroll
        for (int j = 0; j < 4; ++j) {
            int r = (rt * 16 + kg * 4 + j) * 4;
            float t = reds[r] + reds[r + 1] + reds[r + 2] + reds[r + 3];
            lse[rt][j] = gm[rt][j] + __logf(t);
        }

    #pragma unroll
    for (int rt = 0; rt < 4; ++rt)
        #pragma unroll
        for (int j = 0; j < 4; ++j) {
            int grow = row0 + rt * 16 + kg * 4 + j;
            if (grow >= n) continue;
            size_t base = (size_t)grow * DIM;
            float L = lse[rt][j];
            #pragma unroll
            for (int ct = 0; ct < 7; ++ct) {
                if (!cv[ct]) continue;
                int c = colb + ct * 16 + cg;
                float zv = acc[rt][ct][j];
                z[base + c]    = zv;
                outp[base + c] = zv - L;
            }
        }
}

// ---------------------------------------------------------------------------
extern "C" void kernel_launch(void* const* d_in, const int* in_sizes, int n_in,
                              void* d_out, int out_size, void* d_ws, size_t ws_size,
                              hipStream_t stream) {
    int n = in_sizes[0] / 2;       // 50000 nodes
    int e = in_sizes[1] / 2;       // 800000 edges

    const float* x     = (const float*)d_in[0];
    const int*   ei    = (const int*)d_in[1];
    const float* Wg    = (const float*)d_in[2];
    const float* bg    = (const float*)d_in[3];
    const float* gamma = (const float*)d_in[4];
    const float* beta  = (const float*)d_in[5];
    const float* mean  = (const float*)d_in[6];
    const float* var   = (const float*)d_in[7];
    const float* fcw   = (const float*)d_in[8];
    const float* fcb   = (const float*)d_in[9];

    float* out = (float*)d_out;                 // [n, DIM] log_softmax
    float* z   = out + (size_t)n * DIM;         // [n, DIM] logits

    char* wsb = (char*)d_ws;
    float*  deg = (float*)wsb;                          // n (becomes dinv)
    float*  y   = deg + n;                              // 2n
    float2* xs2 = (float2*)(y + 2 * (size_t)n);         // 2n floats
    size_t off = ((size_t)(5 * n) * 4 + 255) & ~(size_t)255;
    bf16x8* Bp = (bf16x8*)(wsb + off);                  // 13*4*448 * 16B
    off += (size_t)NT * 4 * NP * 16;
    float4* Pk = (float4*)(wsb + off);                  // KP * 16B
    off += (size_t)KP * 16;
    float* Ok  = (float*)(wsb + off);                   // KP * 4B

    int nb0 = (n + 255) / 256;
    int prep_blocks = nb0 + 2 + (NT * 4 * NP + 255) / 256;
    int eb4 = (e / 4 + 255) / 256 + 1;

    prep_kernel<<<prep_blocks, 256, 0, stream>>>(Wg, bg, gamma, beta, mean, var,
                                                 fcw, deg, y, Pk, Ok, Bp, n, nb0);
    deg_kernel<<<eb4, 256, 0, stream>>>(ei, deg, e);
    xs_kernel<<<nb0, 256, 0, stream>>>((const float2*)x, deg, xs2, n);
    scatter_kernel<<<eb4, 256, 0, stream>>>(ei, xs2, y, e);

    int gm = (n + 63) / 64;
    gemm_fused<<<gm, 256, 0, stream>>>(deg, y, xs2, Pk, Ok, Bp, fcb, out, z, n);
}

// Round 5
// 207.272 us; speedup vs baseline: 1.3597x; 1.0110x over previous
//
#include <hip/hip_runtime.h>
#include <math.h>

#define DIM 394
#define KP  416      // padded K = 13*32
#define NT  13       // K-steps
#define NP  448      // padded N = 28*16
#define BN_EPS 1e-5f
#define NXCD 8

typedef __bf16 bf16x8 __attribute__((ext_vector_type(8)));
typedef float  f32x4  __attribute__((ext_vector_type(4)));

// wave-uniform layout probe: int64 edge_index has all odd 32-bit words == 0
__device__ inline bool edges_are_int32(const int* ei) {
    int l = threadIdx.x & 63;
    unsigned long long b = __ballot(ei[2 * l + 1] != 0);
    return b != 0ULL;
}

// physical XCD id (0..7) — verified on gfx950 via learn_hip m09
__device__ inline int xcd_id() {
    unsigned id;
    asm volatile("s_getreg_b32 %0, hwreg(HW_REG_XCC_ID)" : "=s"(id));
    return (int)(id & (NXCD - 1));
}

// workgroup-scope fadd: executes in the local (XCD) L2, no sc1 fabric trip.
// Correct here because each XCD only ever touches its own partial buffer.
__device__ inline void xcd_fadd(float* p, float v) {
    __hip_atomic_fetch_add(p, v, __ATOMIC_RELAXED, __HIP_MEMORY_SCOPE_WORKGROUP);
}

// ---------------------------------------------------------------------------
// ws layout (floats):
//   dinv[n] | xs2[2n] | degp[8n] | yp[16n] | (align 256) Bp | Pk | Ok
// ---------------------------------------------------------------------------

// block-role-split prep: zero partials, pack Pk/Ok, pack B fragments
__global__ void prep_kernel(const float* __restrict__ Wg, const float* __restrict__ bg,
                            const float* __restrict__ gamma, const float* __restrict__ beta,
                            const float* __restrict__ mean, const float* __restrict__ var,
                            const float* __restrict__ fcw,
                            float4* zbase, float4* Pk, float* Ok,
                            bf16x8* Bp, int z4, int zb) {
    int b = blockIdx.x, t = threadIdx.x;
    if (b < zb) {                        // zero degp + yp (float4)
        int i = b * 256 + t;
        if (i < z4) zbase[i] = make_float4(0.f, 0.f, 0.f, 0.f);
    } else if (b < zb + 2) {             // Pk/Ok: per-k GCN+BN constants
        int k = (b - zb) * 256 + t;
        if (k < KP) {
            float4 p = make_float4(0.f, 0.f, 0.f, 0.f);
            float o = 0.f;
            if (k < DIM) {
                p.x = Wg[2 * k];
                p.y = Wg[2 * k + 1];
                p.z = bg[k];
                float s = gamma[k] * rsqrtf(var[k] + BN_EPS);
                p.w = s;
                o = beta[k] - s * mean[k];
            }
            Pk[k] = p;
            Ok[k] = o;
        }
    } else {                             // B = fc_w^T packed bf16 fragments
        int idx = (b - zb - 2) * 256 + t;
        if (idx < NT * 4 * NP) {
            int col = idx % NP;
            int r   = idx / NP;          // ks*4 + kc
            int k0  = r * 8;
            bf16x8 v;
            #pragma unroll
            for (int q = 0; q < 8; ++q) {
                int k = k0 + q;
                float f = (col < DIM && k < DIM) ? fcw[col * DIM + k] : 0.0f;
                v[q] = (__bf16)f;
            }
            Bp[idx] = v;
        }
    }
}

// degree count into per-XCD partials (workgroup-scope = L2-local atomics)
__global__ void deg_kernel(const int* __restrict__ ei, float* __restrict__ degp,
                           int e, int n, int np) {
    bool is32 = edges_are_int32(ei);
    float* dp = degp + (np == NXCD ? (size_t)xcd_id() * n : 0);
    int i0 = (blockIdx.x * blockDim.x + threadIdx.x) * 4;
    if (i0 >= e) return;
    if (i0 + 4 <= e && (e & 3) == 0) {
        int d0, d1, d2, d3;
        if (is32) {
            int4 v = *reinterpret_cast<const int4*>(&ei[e + i0]);
            d0 = v.x; d1 = v.y; d2 = v.z; d3 = v.w;
        } else {
            int4 a = *reinterpret_cast<const int4*>(&ei[2 * (e + i0)]);
            int4 b = *reinterpret_cast<const int4*>(&ei[2 * (e + i0) + 4]);
            d0 = a.x; d1 = a.z; d2 = b.x; d3 = b.z;
        }
        if (np == NXCD) {
            xcd_fadd(&dp[d0], 1.0f); xcd_fadd(&dp[d1], 1.0f);
            xcd_fadd(&dp[d2], 1.0f); xcd_fadd(&dp[d3], 1.0f);
        } else {
            atomicAdd(&dp[d0], 1.0f); atomicAdd(&dp[d1], 1.0f);
            atomicAdd(&dp[d2], 1.0f); atomicAdd(&dp[d3], 1.0f);
        }
    } else {
        for (int j = 0; j < 4 && i0 + j < e; ++j) {
            int d = is32 ? ei[e + i0 + j] : ei[2 * (e + i0 + j)];
            if (np == NXCD) xcd_fadd(&dp[d], 1.0f);
            else            atomicAdd(&dp[d], 1.0f);
        }
    }
}

// dinv[i] = rsqrt(1 + sum_p degp[p][i]);  xs2[i] = dinv[i]*x[i]
__global__ void xs_kernel(const float2* __restrict__ x2,
                          const float* __restrict__ degp, float* __restrict__ dinv,
                          float2* __restrict__ xs2, int n, int np) {
    int i = blockIdx.x * blockDim.x + threadIdx.x;
    if (i >= n) return;
    float s = 1.0f;                      // self-loop
    for (int p = 0; p < np; ++p) s += degp[(size_t)p * n + i];
    float di = rsqrtf(s);
    dinv[i] = di;
    float2 xv = x2[i];
    xs2[i] = make_float2(di * xv.x, di * xv.y);
}

// scatter: yp[xcd][d] += xs2[s]  (per-XCD partials, L2-local atomics)
__global__ void scatter_kernel(const int* __restrict__ ei,
                               const float2* __restrict__ xs2,
                               float* __restrict__ yp, int e, int n, int np) {
    bool is32 = edges_are_int32(ei);
    float* y = yp + (np == NXCD ? (size_t)xcd_id() * 2 * n : 0);
    int i0 = (blockIdx.x * blockDim.x + threadIdx.x) * 4;
    if (i0 >= e) return;
    if (i0 + 4 <= e && (e & 3) == 0) {
        int s0, s1, s2, s3, d0, d1, d2, d3;
        if (is32) {
            int4 sv = *reinterpret_cast<const int4*>(&ei[i0]);
            int4 dv = *reinterpret_cast<const int4*>(&ei[e + i0]);
            s0 = sv.x; s1 = sv.y; s2 = sv.z; s3 = sv.w;
            d0 = dv.x; d1 = dv.y; d2 = dv.z; d3 = dv.w;
        } else {
            int4 a = *reinterpret_cast<const int4*>(&ei[2 * i0]);
            int4 b = *reinterpret_cast<const int4*>(&ei[2 * i0 + 4]);
            int4 c = *reinterpret_cast<const int4*>(&ei[2 * (e + i0)]);
            int4 d = *reinterpret_cast<const int4*>(&ei[2 * (e + i0) + 4]);
            s0 = a.x; s1 = a.z; s2 = b.x; s3 = b.z;
            d0 = c.x; d1 = c.z; d2 = d.x; d3 = d.z;
        }
        float2 m0 = xs2[s0], m1 = xs2[s1], m2 = xs2[s2], m3 = xs2[s3];
        if (np == NXCD) {
            xcd_fadd(&y[2 * d0], m0.x); xcd_fadd(&y[2 * d0 + 1], m0.y);
            xcd_fadd(&y[2 * d1], m1.x); xcd_fadd(&y[2 * d1 + 1], m1.y);
            xcd_fadd(&y[2 * d2], m2.x); xcd_fadd(&y[2 * d2 + 1], m2.y);
            xcd_fadd(&y[2 * d3], m3.x); xcd_fadd(&y[2 * d3 + 1], m3.y);
        } else {
            atomicAdd(&y[2 * d0], m0.x); atomicAdd(&y[2 * d0 + 1], m0.y);
            atomicAdd(&y[2 * d1], m1.x); atomicAdd(&y[2 * d1 + 1], m1.y);
            atomicAdd(&y[2 * d2], m2.x); atomicAdd(&y[2 * d2 + 1], m2.y);
            atomicAdd(&y[2 * d3], m3.x); atomicAdd(&y[2 * d3 + 1], m3.y);
        }
    } else {
        for (int j = 0; j < 4 && i0 + j < e; ++j) {
            int s = is32 ? ei[i0 + j]     : ei[2 * (i0 + j)];
            int d = is32 ? ei[e + i0 + j] : ei[2 * (e + i0 + j)];
            float2 m = xs2[s];
            if (np == NXCD) {
                xcd_fadd(&y[2 * d], m.x); xcd_fadd(&y[2 * d + 1], m.y);
            } else {
                atomicAdd(&y[2 * d], m.x); atomicAdd(&y[2 * d + 1], m.y);
            }
        }
    }
}

// ---------------------------------------------------------------------------
// Fused: h = BN(relu(GCN)) on-the-fly -> bf16 MFMA GEMM -> +fc_b
//        -> z store + log_softmax store. 256 thr / 4 waves, BM=64, BN=448.
// A-stage reduces the 8 y-partials inline (coalesced, negligible volume).
// ---------------------------------------------------------------------------
__global__ __launch_bounds__(256, 2)
void gemm_fused(const float* __restrict__ dinv, const float* __restrict__ yp,
                const float2* __restrict__ xs2,
                const float4* __restrict__ Pk, const float* __restrict__ Ok,
                const bf16x8* __restrict__ Bp, const float* __restrict__ fcb,
                float* __restrict__ outp, float* __restrict__ z, int n, int np) {
    __shared__ bf16x8 As[2][256];    // [kc(4)][row(64)] per buffer, 8 KB total

    int tid = threadIdx.x;
    int wv  = tid >> 6;
    int l   = tid & 63;
    int cg  = l & 15;
    int kg  = l >> 4;
    int row0 = blockIdx.x * 64;

    int gi = row0 + l;
    float y0 = 0.f, y1 = 0.f;
    if (gi < n) {
        float di = dinv[gi];
        float2 xv = xs2[gi];
        float sy0 = xv.x, sy1 = xv.y;
        for (int p = 0; p < np; ++p) {
            const float2 yv = *reinterpret_cast<const float2*>(
                &yp[(size_t)p * 2 * n + 2 * gi]);
            sy0 += yv.x;
            sy1 += yv.y;
        }
        y0 = di * sy0;
        y1 = di * sy1;
    }

    f32x4 acc[4][7];
    #pragma unroll
    for (int a = 0; a < 4; ++a)
        #pragma unroll
        for (int b = 0; b < 7; ++b)
            acc[a][b] = (f32x4){0.f, 0.f, 0.f, 0.f};

    auto stageA = [&](int ks, int buf) {
        int kb = ks * 32 + wv * 8;
        bf16x8 hv;
        #pragma unroll
        for (int q = 0; q < 8; ++q) {
            float4 p = Pk[kb + q];
            float t = fmaf(y0, p.x, fmaf(y1, p.y, p.z));
            t = fmaxf(t, 0.f);
            hv[q] = (__bf16)fmaf(p.w, t, Ok[kb + q]);
        }
        As[buf][wv * 64 + l] = hv;
    };

    // lane-fixed B base: fragment (ks, ct) is at bptr[ks*4*448 + ct*16]
    const bf16x8* bptr = Bp + (kg * 448 + wv * 112 + cg);

    bf16x8 Bcur[7], Bnxt[7];
    #pragma unroll
    for (int c = 0; c < 7; ++c) Bcur[c] = bptr[c * 16];
    stageA(0, 0);
    __syncthreads();

    int buf = 0;
    for (int ks = 0; ks < NT; ++ks) {
        if (ks < NT - 1) {
            const bf16x8* bn = bptr + (size_t)(ks + 1) * (4 * 448);
            #pragma unroll
            for (int c = 0; c < 7; ++c) Bnxt[c] = bn[c * 16];
            stageA(ks + 1, buf ^ 1);
        }
        bf16x8 af[4];
        #pragma unroll
        for (int rt = 0; rt < 4; ++rt)
            af[rt] = As[buf][kg * 64 + rt * 16 + cg];
        #pragma unroll
        for (int ct = 0; ct < 7; ++ct)
            #pragma unroll
            for (int rt = 0; rt < 4; ++rt)
                acc[rt][ct] = __builtin_amdgcn_mfma_f32_16x16x32_bf16(
                                  af[rt], Bcur[ct], acc[rt][ct], 0, 0, 0);
        __syncthreads();
        #pragma unroll
        for (int c = 0; c < 7; ++c) Bcur[c] = Bnxt[c];
        buf ^= 1;
    }

    // ---------------- epilogue: bias + log_softmax + stores ----------------
    float* redm = (float*)&As[0][0];
    float* reds = redm + 256;

    int colb = wv * 112;
    float bias[7];
    bool  cv[7];
    #pragma unroll
    for (int ct = 0; ct < 7; ++ct) {
        int c = colb + ct * 16 + cg;
        cv[ct] = (c < DIM);
        bias[ct] = cv[ct] ? fcb[c] : 0.f;
    }
    #pragma unroll
    for (int rt = 0; rt < 4; ++rt)
        #pragma unroll
        for (int ct = 0; ct < 7; ++ct)
            acc[rt][ct] = acc[rt][ct] + bias[ct];

    f32x4 mx[4];
    #pragma unroll
    for (int rt = 0; rt < 4; ++rt) {
        f32x4 m = (f32x4){-1e30f, -1e30f, -1e30f, -1e30f};
        #pragma unroll
        for (int ct = 0; ct < 7; ++ct) {
            if (!cv[ct]) continue;
            #pragma unroll
            for (int j = 0; j < 4; ++j) m[j] = fmaxf(m[j], acc[rt][ct][j]);
        }
        #pragma unroll
        for (int msk = 1; msk < 16; msk <<= 1)
            #pragma unroll
            for (int j = 0; j < 4; ++j)
                m[j] = fmaxf(m[j], __shfl_xor(m[j], msk));
        mx[rt] = m;
    }
    if (cg == 0) {
        #pragma unroll
        for (int rt = 0; rt < 4; ++rt)
            #pragma unroll
            for (int j = 0; j < 4; ++j)
                redm[(rt * 16 + kg * 4 + j) * 4 + wv] = mx[rt][j];
    }
    __syncthreads();
    f32x4 gm[4];
    #pragma unroll
    for (int rt = 0; rt < 4; ++rt)
        #pragma unroll
        for (int j = 0; j < 4; ++j) {
            int r = (rt * 16 + kg * 4 + j) * 4;
            gm[rt][j] = fmaxf(fmaxf(redm[r], redm[r + 1]),
                              fmaxf(redm[r + 2], redm[r + 3]));
        }

    f32x4 sm[4];
    #pragma unroll
    for (int rt = 0; rt < 4; ++rt) {
        f32x4 s = (f32x4){0.f, 0.f, 0.f, 0.f};
        #pragma unroll
        for (int ct = 0; ct < 7; ++ct) {
            if (!cv[ct]) continue;
            #pragma unroll
            for (int j = 0; j < 4; ++j)
                s[j] += __expf(acc[rt][ct][j] - gm[rt][j]);
        }
        #pragma unroll
        for (int msk = 1; msk < 16; msk <<= 1)
            #pragma unroll
            for (int j = 0; j < 4; ++j)
                s[j] += __shfl_xor(s[j], msk);
        sm[rt] = s;
    }
    if (cg == 0) {
        #pragma unroll
        for (int rt = 0; rt < 4; ++rt)
            #pragma unroll
            for (int j = 0; j < 4; ++j)
                reds[(rt * 16 + kg * 4 + j) * 4 + wv] = sm[rt][j];
    }
    __syncthreads();
    f32x4 lse[4];
    #pragma unroll
    for (int rt = 0; rt < 4; ++rt)
        #pragma unroll
        for (int j = 0; j < 4; ++j) {
            int r = (rt * 16 + kg * 4 + j) * 4;
            float t = reds[r] + reds[r + 1] + reds[r + 2] + reds[r + 3];
            lse[rt][j] = gm[rt][j] + __logf(t);
        }

    #pragma unroll
    for (int rt = 0; rt < 4; ++rt)
        #pragma unroll
        for (int j = 0; j < 4; ++j) {
            int grow = row0 + rt * 16 + kg * 4 + j;
            if (grow >= n) continue;
            size_t base = (size_t)grow * DIM;
            float L = lse[rt][j];
            #pragma unroll
            for (int ct = 0; ct < 7; ++ct) {
                if (!cv[ct]) continue;
                int c = colb + ct * 16 + cg;
                float zv = acc[rt][ct][j];
                z[base + c]    = zv;
                outp[base + c] = zv - L;
            }
        }
}

// ---------------------------------------------------------------------------
extern "C" void kernel_launch(void* const* d_in, const int* in_sizes, int n_in,
                              void* d_out, int out_size, void* d_ws, size_t ws_size,
                              hipStream_t stream) {
    int n = in_sizes[0] / 2;       // 50000 nodes
    int e = in_sizes[1] / 2;       // 800000 edges

    const float* x     = (const float*)d_in[0];
    const int*   ei    = (const int*)d_in[1];
    const float* Wg    = (const float*)d_in[2];
    const float* bg    = (const float*)d_in[3];
    const float* gamma = (const float*)d_in[4];
    const float* beta  = (const float*)d_in[5];
    const float* mean  = (const float*)d_in[6];
    const float* var   = (const float*)d_in[7];
    const float* fcw   = (const float*)d_in[8];
    const float* fcb   = (const float*)d_in[9];

    float* out = (float*)d_out;                 // [n, DIM] log_softmax
    float* z   = out + (size_t)n * DIM;         // [n, DIM] logits

    char* wsb = (char*)d_ws;
    float*  dinv = (float*)wsb;                         // n
    float2* xs2  = (float2*)(dinv + n);                 // 2n floats
    float*  degp = (float*)(dinv + 3 * (size_t)n);      // 8n
    float*  yp   = degp + NXCD * (size_t)n;             // 16n
    size_t off = ((size_t)(3 + 24) * n * 4 + 255) & ~(size_t)255;
    bf16x8* Bp = (bf16x8*)(wsb + off);                  // 13*4*448 * 16B
    off += (size_t)NT * 4 * NP * 16;
    float4* Pk = (float4*)(wsb + off);                  // KP * 16B
    off += (size_t)KP * 16;
    float* Ok  = (float*)(wsb + off);                   // KP * 4B
    off += (size_t)KP * 4;

    int np = (ws_size >= off) ? NXCD : 1;    // fallback: single device-scope copy

    int zfloats = np * 3 * n;                // degp + yp actually used
    int z4 = zfloats / 4;                    // n % 4 == 0
    int zb = (z4 + 255) / 256;
    int prep_blocks = zb + 2 + (NT * 4 * NP + 255) / 256;
    int eb4 = (e / 4 + 255) / 256 + 1;
    int nb0 = (n + 255) / 256;

    prep_kernel<<<prep_blocks, 256, 0, stream>>>(Wg, bg, gamma, beta, mean, var,
                                                 fcw, (float4*)degp, Pk, Ok, Bp,
                                                 z4, zb);
    deg_kernel<<<eb4, 256, 0, stream>>>(ei, degp, e, n, np);
    xs_kernel<<<nb0, 256, 0, stream>>>((const float2*)x, degp, dinv, xs2, n, np);
    scatter_kernel<<<eb4, 256, 0, stream>>>(ei, xs2, yp, e, n, np);

    int gm = (n + 63) / 64;
    gemm_fused<<<gm, 256, 0, stream>>>(dinv, yp, xs2, Pk, Ok, Bp, fcb, out, z, n, np);
}